// Round 5
// baseline (129.270 us; speedup 1.0000x reference)
//
#include <hip/hip_runtime.h>
#include <cstdint>

// Shapes fixed by the harness:
// u, delta, z: (b=2, d=1024, l=2048) fp32; A: (d, n=16); B, C: (b, n, l); D: (d,)
constexpr int kD = 1024;
constexpr int kN = 16;
constexpr int kL = 2048;
constexpr int BLOCK = 1024;      // R5: 16 waves/block = TWO rows per block
constexpr int TPR   = 512;       // threads per row
constexpr int RPB   = BLOCK / TPR;  // 2 rows per block
constexpr int T  = kL / TPR;     // 4 timesteps per thread (one float4)
constexpr int NW = TPR / 64;     // 8 waves per row-group
constexpr int NQ = 4;            // states per pass (quarter of kN)
constexpr int NP = kN / NQ;      // 4 passes
constexpr float LOG2E = 1.44269504088896340736f;

// s_waitcnt immediate (gfx9 encoding: vm[3:0]+[15:14], exp[6:4], lgkm[11:8])
constexpr unsigned WAIT_LGKM0 = 0xC07F;  // lgkmcnt(0); vmcnt/expcnt = no-wait

__device__ __forceinline__ float fast_exp2(float x) { return __builtin_amdgcn_exp2f(x); }
__device__ __forceinline__ float fast_exp(float x)  { return __builtin_amdgcn_exp2f(x * LOG2E); }
__device__ __forceinline__ float softplus_f(float x) {
  return (x > 20.0f) ? x : __logf(1.0f + fast_exp(x));
}

// DPP move with explicit 'old' (identity) — used only for the lane-exclusive
// prefix in the apply phase.
template<int CTRL, int RM>
__device__ __forceinline__ float dppf(float old_, float src) {
  union U { float f; int i; };
  U o, s, r; o.f = old_; s.f = src;
  r.i = __builtin_amdgcn_update_dpp(o.i, s.i, CTRL, RM, 0xF, false);
  return r.f;
}

__device__ __forceinline__ float readlane_f(float v, int l) {
  union U { float f; int i; };
  U a, r; a.f = v;
  r.i = __builtin_amdgcn_readlane(a.i, l);
  return r.f;
}

// R12: hot 64-lane scan in raw DPP asm. bound_ctrl off + row_mask => invalid
// lanes DON'T WRITE dest, so in-place
//   v_fmac_f32_dpp x, x, a   (x += dpp(x)*a; boundary lanes keep x)
//   v_mul_f32_dpp  a, a, a   (a *= dpp(a);   boundary lanes keep a)
// is one masked Hillis-Steele step in 2 insts/state. State-inner interleave
// gives 8-inst spacing for the VALU->DPP hazard; s_nop 1 covers entry.
#define SCAN_FM(X, A, CTRL) \
  "v_fmac_f32_dpp " X ", " X ", " A " " CTRL "\n\t" \
  "v_mul_f32_dpp "  A ", " A ", " A " " CTRL "\n\t"
#define SCAN_STEP(CTRL) \
  SCAN_FM("%0","%4",CTRL) SCAN_FM("%1","%5",CTRL) \
  SCAN_FM("%2","%6",CTRL) SCAN_FM("%3","%7",CTRL)

// One selective-scan step for element i of a state: a = exp2(spl*A);
// h = a*h + du*B; p *= a; y += C*h; cp = C*p.
#define SSTEP(i, Bc, Cc) {                         \
    float a_ = fast_exp2(spl[i] * Arn);            \
    h = fmaf(a_, h, du[i] * (Bc));                 \
    p *= a_;                                       \
    y[i] = fmaf((Cc), h, y[i]);                    \
    cp[n][i] = (Cc) * p; }

// Single-arg launch_bounds ONLY: any min-waves hint triggers a spill cascade
// (prior session: R2/R3/R6 notes). Keep VGPR <= 64 (8 waves/SIMD)!
// R5: two rows per 1024-thread block — CU occupancy no longer depends on
// multi-block co-residency (measured ~1.4 blocks/CU at 512 threads despite
// a static cap of 4; 16 waves/block reaches 32 waves/CU with just 2 blocks).
__global__ __launch_bounds__(BLOCK)
void selscan_kernel(const float* __restrict__ u,  const float* __restrict__ dl,
                    const float* __restrict__ A,  const float* __restrict__ Bm,
                    const float* __restrict__ Cm, const float* __restrict__ Dv,
                    const float* __restrict__ zm, float* __restrict__ out)
{
  const int tid  = threadIdx.x;
  const int g    = tid >> 9;            // row-group within block (0/1)
  const int t    = tid & (TPR - 1);     // thread within row
  const int lane = tid & 63;
  const int wl   = (tid >> 6) & (NW - 1); // wave within row-group

  const int row  = blockIdx.x * RPB + g;  // b*kD + d  (pairs never straddle b)
  const int b    = row >> 10;             // kD = 1024
  const int d    = row & (kD - 1);

  const size_t roff = (size_t)row * kL;
  const float4* u4 = reinterpret_cast<const float4*>(u  + roff);
  const float4* d4 = reinterpret_cast<const float4*>(dl + roff);
  const float4* B4all = reinterpret_cast<const float4*>(Bm + (size_t)b * kN * kL);
  const float4* C4all = reinterpret_cast<const float4*>(Cm + (size_t)b * kN * kL);

  // Per-thread chunk [t*T, t*T+T): softplus(delta)*LOG2E and delta*u in regs.
  // u itself is NOT carried — re-loaded in the epilogue.
  float spl[T], du[T];
  {
    float4 a0 = u4[t];
    float4 b0 = d4[t];
    float uv[T] = {a0.x, a0.y, a0.z, a0.w};
    float dv[T] = {b0.x, b0.y, b0.z, b0.w};
    #pragma unroll
    for (int i = 0; i < T; ++i) {
      float s = softplus_f(dv[i]);
      du[i]  = s * uv[i];
      spl[i] = s * LOG2E;              // exp2 arg = spl*A == sp*LOG2E*A
    }
  }

  float y[T];
  #pragma unroll
  for (int i = 0; i < T; ++i) y[i] = 0.0f;

  // Per-row-group, per-pass wave-total buffers: (a,x) per (wave, state).
  // 2*4*8*4*8B = 2 KB. Separate buffer per pass -> no end-of-pass barrier.
  __shared__ float2 sAX[RPB][NP][NW][NQ];

  #pragma unroll 1                      // passes sequential: live-range control
  for (int q = 0; q < NP; ++q) {
    // A quarter: uniform address per row-group. LOG2E folded into spl[].
    float Aq[NQ];
    {
      const float4 av = *reinterpret_cast<const float4*>(A + (size_t)d * kN + q * NQ);
      Aq[0] = av.x; Aq[1] = av.y; Aq[2] = av.z; Aq[3] = av.w;
    }
    const float4* Bq = B4all + (size_t)(q * NQ) * (kL / 4);
    const float4* Cq = C4all + (size_t)(q * NQ) * (kL / 4);

    // ---- Pass A with the cp-trick: C consumed at load time.
    // h_i = pp_i*h0 + hl_i (linearity) =>  y_i += C_i*hl_i here,
    // cp_i = C_i*pp_i saved; post-scan apply is pure register FMA.
    // Loads at point of use (R2 form): compiler hoists across the unrolled
    // n-loop as register slack allows (explicit prefetch regressed, R1/R3/R4).
    float cp[NQ][T];
    float cA[NQ], cX[NQ];
    #pragma unroll
    for (int n = 0; n < NQ; ++n) {
      float4 b0 = Bq[n * (kL / 4) + t];
      float4 c0 = Cq[n * (kL / 4) + t];
      const float Arn = Aq[n];
      float h = 0.0f, p = 1.0f;
      SSTEP(0, b0.x, c0.x) SSTEP(1, b0.y, c0.y)
      SSTEP(2, b0.z, c0.z) SSTEP(3, b0.w, c0.w)
      cA[n] = p; cX[n] = h;
    }

    // ---- Wave-level scan on chunk aggregates — raw DPP, 2 inst/state/step.
    {
      float x0=cX[0], x1=cX[1], x2=cX[2], x3=cX[3];
      float a0_=cA[0], a1_=cA[1], a2_=cA[2], a3_=cA[3];
      asm("s_nop 1\n\t"
          SCAN_STEP("row_shr:1 row_mask:0xf bank_mask:0xf")
          SCAN_STEP("row_shr:2 row_mask:0xf bank_mask:0xf")
          SCAN_STEP("row_shr:4 row_mask:0xf bank_mask:0xf")
          SCAN_STEP("row_shr:8 row_mask:0xf bank_mask:0xf")
          SCAN_STEP("row_bcast:15 row_mask:0xa bank_mask:0xf")
          SCAN_STEP("row_bcast:31 row_mask:0xc bank_mask:0xf")
          : "+v"(x0), "+v"(x1), "+v"(x2), "+v"(x3),
            "+v"(a0_), "+v"(a1_), "+v"(a2_), "+v"(a3_));
      cX[0]=x0; cX[1]=x1; cX[2]=x2; cX[3]=x3;
      cA[0]=a0_; cA[1]=a1_; cA[2]=a2_; cA[3]=a3_;
    }

    // ---- Publish wave totals (lane 63 holds them), ONE barrier (raw: lgkm
    // drain only — no vmcnt drain, so any in-flight globals keep flying).
    if (lane == 63) {
      #pragma unroll
      for (int n = 0; n < NQ; ++n) sAX[g][q][wl][n] = make_float2(cA[n], cX[n]);
    }
    __builtin_amdgcn_s_waitcnt(WAIT_LGKM0);
    __builtin_amdgcn_s_barrier();

    // ---- Parallel exclusive fold: all 7 candidate aggregates load
    // concurrently (one lgkm wait; 4-lane-group same-address broadcast =
    // conflict-free), then an identity-padded select+fma chain. wl is
    // wave-uniform. ex = x[wl-1] + a[wl-1]*(x[wl-2] + ...).
    float ex = 0.0f;                     // lane n<4: exclusive x-prefix, state n
    {
      const int n = lane & (NQ - 1);
      float2 s[NW - 1];
      #pragma unroll
      for (int w2 = 0; w2 < NW - 1; ++w2) s[w2] = sAX[g][q][w2][n];
      #pragma unroll
      for (int w2 = 0; w2 < NW - 1; ++w2) {
        float aa = (w2 < wl) ? s[w2].x : 1.0f;
        float xx = (w2 < wl) ? s[w2].y : 0.0f;
        ex = aa * ex + xx;
      }
    }

    // ---- Apply: y_i += cp_i * h0   (pure FMA; exn broadcast via readlane)
    #pragma unroll
    for (int n = 0; n < NQ; ++n) {
      float al = dppf<0x138,0xF>(1.0f, cA[n]);   // lane-exclusive prefix
      float xl = dppf<0x138,0xF>(0.0f, cX[n]);
      float exn = readlane_f(ex, n);             // scalar: wave-exclusive x
      float h0 = al * exn + xl;                  // state entering this chunk
      #pragma unroll
      for (int i = 0; i < T; ++i) y[i] += cp[n][i] * h0;
    }
    // no end-of-pass barrier: each pass uses its own sAX buffer
  }

  // ---- Epilogue: + u*D, * silu(z), store  (u re-loaded here)
  const float Dd = Dv[d];
  const float4* z4 = reinterpret_cast<const float4*>(zm + roff);
  float4 z0 = z4[t];
  float4 ua = u4[t];
  float zv[T] = {z0.x, z0.y, z0.z, z0.w};
  float uv[T] = {ua.x, ua.y, ua.z, ua.w};
  float ov[T];
  #pragma unroll
  for (int i = 0; i < T; ++i) {
    float yy  = y[i] + uv[i] * Dd;
    float sig = 1.0f / (1.0f + fast_exp(-zv[i]));
    ov[i] = yy * zv[i] * sig;
  }
  reinterpret_cast<float4*>(out + roff)[t] = make_float4(ov[0], ov[1], ov[2], ov[3]);
}

extern "C" void kernel_launch(void* const* d_in, const int* in_sizes, int n_in,
                              void* d_out, int out_size, void* d_ws, size_t ws_size,
                              hipStream_t stream)
{
  const float* u  = (const float*)d_in[0];
  const float* dl = (const float*)d_in[1];
  const float* A  = (const float*)d_in[2];
  const float* Bm = (const float*)d_in[3];
  const float* Cm = (const float*)d_in[4];
  const float* Dv = (const float*)d_in[5];
  const float* zm = (const float*)d_in[6];
  float* out = (float*)d_out;
  const int rows = in_sizes[0] / kL;   // b*d = 2048
  selscan_kernel<<<rows / RPB, BLOCK, 0, stream>>>(u, dl, A, Bm, Cm, Dv, zm, out);
}

// Round 6
// 124.092 us; speedup vs baseline: 1.0417x; 1.0417x over previous
//
#include <hip/hip_runtime.h>
#include <cstdint>

// Shapes fixed by the harness:
// u, delta, z: (b=2, d=1024, l=2048) fp32; A: (d, n=16); B, C: (b, n, l); D: (d,)
constexpr int kD = 1024;
constexpr int kN = 16;
constexpr int kL = 2048;
constexpr int BLOCK = 512;       // R6: back to R2's proven 512-thread blocks
constexpr int T  = kL / BLOCK;   // 4 timesteps per thread (one float4)
constexpr int NW = BLOCK / 64;   // 8 waves per block
constexpr int NQ = 4;            // states per pass (quarter of kN)
constexpr int NP = kN / NQ;      // 4 passes
constexpr int PADN = NW + NW - 1;  // 7 identity rows + 8 wave rows
constexpr float LOG2E = 1.44269504088896340736f;

// s_waitcnt immediate (gfx9 encoding: vm[3:0]+[15:14], exp[6:4], lgkm[11:8])
constexpr unsigned WAIT_LGKM0 = 0xC07F;  // lgkmcnt(0); vmcnt/expcnt = no-wait

__device__ __forceinline__ float fast_exp2(float x) { return __builtin_amdgcn_exp2f(x); }
__device__ __forceinline__ float fast_exp(float x)  { return __builtin_amdgcn_exp2f(x * LOG2E); }
__device__ __forceinline__ float softplus_f(float x) {
  return (x > 20.0f) ? x : __logf(1.0f + fast_exp(x));
}

// DPP move with explicit 'old' (identity) — used only for the lane-exclusive
// prefix in the apply phase.
template<int CTRL, int RM>
__device__ __forceinline__ float dppf(float old_, float src) {
  union U { float f; int i; };
  U o, s, r; o.f = old_; s.f = src;
  r.i = __builtin_amdgcn_update_dpp(o.i, s.i, CTRL, RM, 0xF, false);
  return r.f;
}

__device__ __forceinline__ float readlane_f(float v, int l) {
  union U { float f; int i; };
  U a, r; a.f = v;
  r.i = __builtin_amdgcn_readlane(a.i, l);
  return r.f;
}

// R12: hot 64-lane scan in raw DPP asm. bound_ctrl off + row_mask => invalid
// lanes DON'T WRITE dest, so in-place
//   v_fmac_f32_dpp x, x, a   (x += dpp(x)*a; boundary lanes keep x)
//   v_mul_f32_dpp  a, a, a   (a *= dpp(a);   boundary lanes keep a)
// is one masked Hillis-Steele step in 2 insts/state. State-inner interleave
// gives 8-inst spacing for the VALU->DPP hazard; s_nop 1 covers entry.
#define SCAN_FM(X, A, CTRL) \
  "v_fmac_f32_dpp " X ", " X ", " A " " CTRL "\n\t" \
  "v_mul_f32_dpp "  A ", " A ", " A " " CTRL "\n\t"
#define SCAN_STEP(CTRL) \
  SCAN_FM("%0","%4",CTRL) SCAN_FM("%1","%5",CTRL) \
  SCAN_FM("%2","%6",CTRL) SCAN_FM("%3","%7",CTRL)

// One selective-scan step for element i of a state: a = exp2(spl*A);
// h = a*h + du*B; p *= a; y += C*h; cp = C*p.
#define SSTEP(i, Bc, Cc) {                         \
    float a_ = fast_exp2(spl[i] * Arn);            \
    h = fmaf(a_, h, du[i] * (Bc));                 \
    p *= a_;                                       \
    y[i] = fmaf((Cc), h, y[i]);                    \
    cp[n][i] = (Cc) * p; }

// Single-arg launch_bounds ONLY: any min-waves hint triggers a spill cascade
// (prior session: R2/R3/R6 notes). Keep VGPR <= 64 (8 waves/SIMD)!
// R6 = R2 (proven best, 47.6us) + identity-padded fold (kills 14 v_cndmask
// per pass) + raw lgkm-only barrier (no vmcnt drain).
__global__ __launch_bounds__(BLOCK)
void selscan_kernel(const float* __restrict__ u,  const float* __restrict__ dl,
                    const float* __restrict__ A,  const float* __restrict__ Bm,
                    const float* __restrict__ Cm, const float* __restrict__ Dv,
                    const float* __restrict__ zm, float* __restrict__ out)
{
  const int row  = blockIdx.x;          // b*kD + d
  const int b    = row >> 10;           // kD = 1024
  const int d    = row & (kD - 1);
  const int tid  = threadIdx.x;
  const int lane = tid & 63;
  const int wid  = tid >> 6;

  const size_t roff = (size_t)row * kL;
  const float4* u4 = reinterpret_cast<const float4*>(u  + roff);
  const float4* d4 = reinterpret_cast<const float4*>(dl + roff);
  const float4* B4all = reinterpret_cast<const float4*>(Bm + (size_t)b * kN * kL);
  const float4* C4all = reinterpret_cast<const float4*>(Cm + (size_t)b * kN * kL);

  // Per-pass aggregate table with a 7-row IDENTITY PAD in front:
  // entries [q][0..NW-2]     = (a=1, x=0)   (filled once below)
  // entries [q][NW-1 + w]    = wave w's inclusive totals
  // Wave wid's exclusive set is then entries [wid .. wid+NW-2] — read with
  // NO comparisons/selects (identities are exact no-ops in the fma chain).
  // 4*15*4*8B = 1920 B.
  __shared__ float2 sAXp[NP][PADN][NQ];

  // Pad fill (once; ordered before any fold-read by pass 0's barrier).
  if (tid < 128) {
    const int qq = tid >> 5, rem = tid & 31;
    if (rem < (NW - 1) * NQ) {
      sAXp[qq][rem >> 2][rem & 3] = make_float2(1.0f, 0.0f);
    }
  }

  // Per-thread chunk [tid*T, tid*T+T): softplus(delta)*LOG2E and delta*u in
  // regs. u itself is NOT carried — re-loaded in the epilogue.
  float spl[T], du[T];
  {
    float4 a0 = u4[tid];
    float4 b0 = d4[tid];
    float uv[T] = {a0.x, a0.y, a0.z, a0.w};
    float dv[T] = {b0.x, b0.y, b0.z, b0.w};
    #pragma unroll
    for (int i = 0; i < T; ++i) {
      float s = softplus_f(dv[i]);
      du[i]  = s * uv[i];
      spl[i] = s * LOG2E;              // exp2 arg = spl*A == sp*LOG2E*A
    }
  }

  float y[T];
  #pragma unroll
  for (int i = 0; i < T; ++i) y[i] = 0.0f;

  #pragma unroll 1                      // passes sequential: live-range control
  for (int q = 0; q < NP; ++q) {
    // A quarter: uniform address. LOG2E folded into spl[].
    float Aq[NQ];
    {
      const float4 av = *reinterpret_cast<const float4*>(A + (size_t)d * kN + q * NQ);
      Aq[0] = av.x; Aq[1] = av.y; Aq[2] = av.z; Aq[3] = av.w;
    }
    const float4* Bq = B4all + (size_t)(q * NQ) * (kL / 4);
    const float4* Cq = C4all + (size_t)(q * NQ) * (kL / 4);

    // ---- Pass A with the cp-trick: C consumed at load time.
    // h_i = pp_i*h0 + hl_i (linearity) =>  y_i += C_i*hl_i here,
    // cp_i = C_i*pp_i saved; post-scan apply is pure register FMA.
    // Loads at point of use (R2 form): compiler hoists across the unrolled
    // n-loop as register slack allows (explicit prefetch regressed, R1/R3/R4).
    float cp[NQ][T];
    float cA[NQ], cX[NQ];
    #pragma unroll
    for (int n = 0; n < NQ; ++n) {
      float4 b0 = Bq[n * (kL / 4) + tid];
      float4 c0 = Cq[n * (kL / 4) + tid];
      const float Arn = Aq[n];
      float h = 0.0f, p = 1.0f;
      SSTEP(0, b0.x, c0.x) SSTEP(1, b0.y, c0.y)
      SSTEP(2, b0.z, c0.z) SSTEP(3, b0.w, c0.w)
      cA[n] = p; cX[n] = h;
    }

    // ---- Wave-level scan on chunk aggregates — raw DPP, 2 inst/state/step.
    {
      float x0=cX[0], x1=cX[1], x2=cX[2], x3=cX[3];
      float a0_=cA[0], a1_=cA[1], a2_=cA[2], a3_=cA[3];
      asm("s_nop 1\n\t"
          SCAN_STEP("row_shr:1 row_mask:0xf bank_mask:0xf")
          SCAN_STEP("row_shr:2 row_mask:0xf bank_mask:0xf")
          SCAN_STEP("row_shr:4 row_mask:0xf bank_mask:0xf")
          SCAN_STEP("row_shr:8 row_mask:0xf bank_mask:0xf")
          SCAN_STEP("row_bcast:15 row_mask:0xa bank_mask:0xf")
          SCAN_STEP("row_bcast:31 row_mask:0xc bank_mask:0xf")
          : "+v"(x0), "+v"(x1), "+v"(x2), "+v"(x3),
            "+v"(a0_), "+v"(a1_), "+v"(a2_), "+v"(a3_));
      cX[0]=x0; cX[1]=x1; cX[2]=x2; cX[3]=x3;
      cA[0]=a0_; cA[1]=a1_; cA[2]=a2_; cA[3]=a3_;
    }

    // ---- Publish wave totals (lane 63 holds them), ONE barrier (raw: lgkm
    // drain only — no vmcnt drain, so in-flight globals keep flying).
    if (lane == 63) {
      #pragma unroll
      for (int n = 0; n < NQ; ++n)
        sAXp[q][(NW - 1) + wid][n] = make_float2(cA[n], cX[n]);
    }
    __builtin_amdgcn_s_waitcnt(WAIT_LGKM0);
    __builtin_amdgcn_s_barrier();

    // ---- Parallel exclusive fold, select-free: read the 7 entries at
    // [wid+k] (k=0..6) — identity pad makes out-of-range waves no-ops.
    // All 7 loads issue concurrently (16-lane same-address broadcast per
    // n-group = conflict-free); then a 7-FMA chain.
    // ex = fold oldest-first: ex = a*ex + x over waves 0..wid-1.
    float ex = 0.0f;                     // lane n<4: exclusive x-prefix, state n
    {
      const int n = lane & (NQ - 1);
      #pragma unroll
      for (int k = 0; k < NW - 1; ++k) {
        float2 s = sAXp[q][wid + k][n];
        ex = s.x * ex + s.y;
      }
    }

    // ---- Apply: y_i += cp_i * h0   (pure FMA; exn broadcast via readlane)
    #pragma unroll
    for (int n = 0; n < NQ; ++n) {
      float al = dppf<0x138,0xF>(1.0f, cA[n]);   // lane-exclusive prefix
      float xl = dppf<0x138,0xF>(0.0f, cX[n]);
      float exn = readlane_f(ex, n);             // scalar: wave-exclusive x
      float h0 = al * exn + xl;                  // state entering this chunk
      #pragma unroll
      for (int i = 0; i < T; ++i) y[i] += cp[n][i] * h0;
    }
    // no end-of-pass barrier: each pass uses its own sAXp buffer
  }

  // ---- Epilogue: + u*D, * silu(z), store  (u re-loaded here)
  const float Dd = Dv[d];
  const float4* z4 = reinterpret_cast<const float4*>(zm + roff);
  float4 z0 = z4[tid];
  float4 ua = u4[tid];
  float zv[T] = {z0.x, z0.y, z0.z, z0.w};
  float uv[T] = {ua.x, ua.y, ua.z, ua.w};
  float ov[T];
  #pragma unroll
  for (int i = 0; i < T; ++i) {
    float yy  = y[i] + uv[i] * Dd;
    float sig = 1.0f / (1.0f + fast_exp(-zv[i]));
    ov[i] = yy * zv[i] * sig;
  }
  reinterpret_cast<float4*>(out + roff)[tid] = make_float4(ov[0], ov[1], ov[2], ov[3]);
}

extern "C" void kernel_launch(void* const* d_in, const int* in_sizes, int n_in,
                              void* d_out, int out_size, void* d_ws, size_t ws_size,
                              hipStream_t stream)
{
  const float* u  = (const float*)d_in[0];
  const float* dl = (const float*)d_in[1];
  const float* A  = (const float*)d_in[2];
  const float* Bm = (const float*)d_in[3];
  const float* Cm = (const float*)d_in[4];
  const float* Dv = (const float*)d_in[5];
  const float* zm = (const float*)d_in[6];
  float* out = (float*)d_out;
  const int rows = in_sizes[0] / kL;   // b*d = 2048
  selscan_kernel<<<rows, BLOCK, 0, stream>>>(u, dl, A, Bm, Cm, Dv, zm, out);
}

// Round 7
// 120.700 us; speedup vs baseline: 1.0710x; 1.0281x over previous
//
#include <hip/hip_runtime.h>
#include <cstdint>

// Shapes fixed by the harness:
// u, delta, z: (b=2, d=1024, l=2048) fp32; A: (d, n=16); B, C: (b, n, l); D: (d,)
constexpr int kD = 1024;
constexpr int kN = 16;
constexpr int kL = 2048;
constexpr int BLOCK = 512;
constexpr int T  = kL / BLOCK;   // 4 timesteps per thread (one float4)
constexpr int NW = BLOCK / 64;   // 8 waves per block
constexpr int NQ = 4;            // states per pass (quarter of kN)
constexpr int NP = kN / NQ;      // 4 passes
constexpr int PADN = NW + NW - 1;  // 7 identity rows + 8 wave rows
constexpr float LOG2E = 1.44269504088896340736f;

// s_waitcnt immediate (gfx9 encoding: vm[3:0]+[15:14], exp[6:4], lgkm[11:8])
constexpr unsigned WAIT_LGKM0 = 0xC07F;  // lgkmcnt(0); vmcnt/expcnt = no-wait

__device__ __forceinline__ float fast_exp2(float x) { return __builtin_amdgcn_exp2f(x); }
__device__ __forceinline__ float fast_exp(float x)  { return __builtin_amdgcn_exp2f(x * LOG2E); }
__device__ __forceinline__ float softplus_f(float x) {
  return (x > 20.0f) ? x : __logf(1.0f + fast_exp(x));
}

// DPP move with explicit 'old' (identity) — used only for the lane-exclusive
// prefix in the apply phase.
template<int CTRL, int RM>
__device__ __forceinline__ float dppf(float old_, float src) {
  union U { float f; int i; };
  U o, s, r; o.f = old_; s.f = src;
  r.i = __builtin_amdgcn_update_dpp(o.i, s.i, CTRL, RM, 0xF, false);
  return r.f;
}

__device__ __forceinline__ float readlane_f(float v, int l) {
  union U { float f; int i; };
  U a, r; a.f = v;
  r.i = __builtin_amdgcn_readlane(a.i, l);
  return r.f;
}

// R12: hot 64-lane scan in raw DPP asm. bound_ctrl off + row_mask => invalid
// lanes DON'T WRITE dest, so in-place
//   v_fmac_f32_dpp x, x, a   (x += dpp(x)*a; boundary lanes keep x)
//   v_mul_f32_dpp  a, a, a   (a *= dpp(a);   boundary lanes keep a)
// is one masked Hillis-Steele step in 2 insts/state. State-inner interleave
// gives 8-inst spacing for the VALU->DPP hazard; s_nop 1 covers entry.
#define SCAN_FM(X, A, CTRL) \
  "v_fmac_f32_dpp " X ", " X ", " A " " CTRL "\n\t" \
  "v_mul_f32_dpp "  A ", " A ", " A " " CTRL "\n\t"
#define SCAN_STEP(CTRL) \
  SCAN_FM("%0","%4",CTRL) SCAN_FM("%1","%5",CTRL) \
  SCAN_FM("%2","%6",CTRL) SCAN_FM("%3","%7",CTRL)

// One selective-scan step for element i of a state: a = exp2(spl*A);
// h = a*h + du*B; p *= a; y += C*h; cp = C*p.
#define SSTEP(i, Bc, Cc) {                         \
    float a_ = fast_exp2(spl[i] * Arn);            \
    h = fmaf(a_, h, du[i] * (Bc));                 \
    p *= a_;                                       \
    y[i] = fmaf((Cc), h, y[i]);                    \
    cp[n][i] = (Cc) * p; }

// Single-arg launch_bounds ONLY: any min-waves hint triggers a spill cascade
// (prior session: R2/R3/R6 notes). Keep VGPR <= 64 (8 waves/SIMD)!
// R7 = R6 (proven best, 42.4us) with the 4 per-pass block-wide s_barriers
// replaced by DIRECTIONAL LDS-flag sync: wave w's fold needs only waves
// 0..w-1's totals, so wave w spin-waits (acquire) on mask bits (1<<w)-1 and
// producers release-OR their bit after publishing. Wave 0 never waits ->
// waves pipeline across passes instead of convoying at barriers (R5 showed
// wider sync = worse; R6 showed softer sync = better). One trivial prologue
// barrier orders pad/mask init; deadlock-free (all 8 waves co-resident,
// producers never block on consumers).
__global__ __launch_bounds__(BLOCK)
void selscan_kernel(const float* __restrict__ u,  const float* __restrict__ dl,
                    const float* __restrict__ A,  const float* __restrict__ Bm,
                    const float* __restrict__ Cm, const float* __restrict__ Dv,
                    const float* __restrict__ zm, float* __restrict__ out)
{
  const int row  = blockIdx.x;          // b*kD + d
  const int b    = row >> 10;           // kD = 1024
  const int d    = row & (kD - 1);
  const int tid  = threadIdx.x;
  const int lane = tid & 63;
  const int wid  = tid >> 6;

  const size_t roff = (size_t)row * kL;
  const float4* u4 = reinterpret_cast<const float4*>(u  + roff);
  const float4* d4 = reinterpret_cast<const float4*>(dl + roff);
  const float4* B4all = reinterpret_cast<const float4*>(Bm + (size_t)b * kN * kL);
  const float4* C4all = reinterpret_cast<const float4*>(Cm + (size_t)b * kN * kL);

  // Per-pass aggregate table with a 7-row IDENTITY PAD in front:
  // entries [q][0..NW-2]  = (a=1, x=0);  [q][NW-1 + w] = wave w's totals.
  // Wave wid's exclusive set = entries [wid .. wid+NW-2], select-free.
  __shared__ float2 sAXp[NP][PADN][NQ];
  // Per-pass publish mask: bit w set <=> wave w's totals are in sAXp[q].
  __shared__ uint32_t smask[NP];

  // Pad + mask init (once; ordered by the single prologue barrier below).
  if (tid < 128) {
    const int qq = tid >> 5, rem = tid & 31;
    if (rem < (NW - 1) * NQ) {
      sAXp[qq][rem >> 2][rem & 3] = make_float2(1.0f, 0.0f);
    }
  }
  if (tid < NP) smask[tid] = 0u;

  // Per-thread chunk [tid*T, tid*T+T): softplus(delta)*LOG2E and delta*u in
  // regs. u itself is NOT carried — re-loaded in the epilogue.
  float spl[T], du[T];
  {
    float4 a0 = u4[tid];
    float4 b0 = d4[tid];

    // The ONLY block-wide barrier: orders pad/mask init before any fold/OR.
    // Raw (lgkm-only) so the u/delta loads above stay in flight across it.
    __builtin_amdgcn_s_waitcnt(WAIT_LGKM0);
    __builtin_amdgcn_s_barrier();

    float uv[T] = {a0.x, a0.y, a0.z, a0.w};
    float dv[T] = {b0.x, b0.y, b0.z, b0.w};
    #pragma unroll
    for (int i = 0; i < T; ++i) {
      float s = softplus_f(dv[i]);
      du[i]  = s * uv[i];
      spl[i] = s * LOG2E;              // exp2 arg = spl*A == sp*LOG2E*A
    }
  }

  float y[T];
  #pragma unroll
  for (int i = 0; i < T; ++i) y[i] = 0.0f;

  #pragma unroll 1                      // passes sequential: live-range control
  for (int q = 0; q < NP; ++q) {
    // A quarter: uniform address. LOG2E folded into spl[].
    float Aq[NQ];
    {
      const float4 av = *reinterpret_cast<const float4*>(A + (size_t)d * kN + q * NQ);
      Aq[0] = av.x; Aq[1] = av.y; Aq[2] = av.z; Aq[3] = av.w;
    }
    const float4* Bq = B4all + (size_t)(q * NQ) * (kL / 4);
    const float4* Cq = C4all + (size_t)(q * NQ) * (kL / 4);

    // ---- Pass A with the cp-trick: C consumed at load time.
    // h_i = pp_i*h0 + hl_i (linearity) =>  y_i += C_i*hl_i here,
    // cp_i = C_i*pp_i saved; post-scan apply is pure register FMA.
    // Loads at point of use (R2 form): compiler hoists across the unrolled
    // n-loop as register slack allows (explicit prefetch regressed, R1/R3/R4).
    float cp[NQ][T];
    float cA[NQ], cX[NQ];
    #pragma unroll
    for (int n = 0; n < NQ; ++n) {
      float4 b0 = Bq[n * (kL / 4) + tid];
      float4 c0 = Cq[n * (kL / 4) + tid];
      const float Arn = Aq[n];
      float h = 0.0f, p = 1.0f;
      SSTEP(0, b0.x, c0.x) SSTEP(1, b0.y, c0.y)
      SSTEP(2, b0.z, c0.z) SSTEP(3, b0.w, c0.w)
      cA[n] = p; cX[n] = h;
    }

    // ---- Wave-level scan on chunk aggregates — raw DPP, 2 inst/state/step.
    {
      float x0=cX[0], x1=cX[1], x2=cX[2], x3=cX[3];
      float a0_=cA[0], a1_=cA[1], a2_=cA[2], a3_=cA[3];
      asm("s_nop 1\n\t"
          SCAN_STEP("row_shr:1 row_mask:0xf bank_mask:0xf")
          SCAN_STEP("row_shr:2 row_mask:0xf bank_mask:0xf")
          SCAN_STEP("row_shr:4 row_mask:0xf bank_mask:0xf")
          SCAN_STEP("row_shr:8 row_mask:0xf bank_mask:0xf")
          SCAN_STEP("row_bcast:15 row_mask:0xa bank_mask:0xf")
          SCAN_STEP("row_bcast:31 row_mask:0xc bank_mask:0xf")
          : "+v"(x0), "+v"(x1), "+v"(x2), "+v"(x3),
            "+v"(a0_), "+v"(a1_), "+v"(a2_), "+v"(a3_));
      cX[0]=x0; cX[1]=x1; cX[2]=x2; cX[3]=x3;
      cA[0]=a0_; cA[1]=a1_; cA[2]=a2_; cA[3]=a3_;
    }

    // ---- Publish wave totals (lane 63 holds them), then RELEASE our bit.
    // Release ordering makes the 4 ds_writes visible before the OR lands.
    if (lane == 63) {
      #pragma unroll
      for (int n = 0; n < NQ; ++n)
        sAXp[q][(NW - 1) + wid][n] = make_float2(cA[n], cX[n]);
      __hip_atomic_fetch_or(&smask[q], 1u << wid,
                            __ATOMIC_RELEASE, __HIP_MEMORY_SCOPE_WORKGROUP);
    }

    // ---- Directional wait: wave w needs only waves 0..w-1. Wave 0 falls
    // straight through and starts pass q+1's loads (pipeline stagger).
    // 64-lane same-address spin read = LDS broadcast, conflict-free.
    {
      const uint32_t need = (1u << wid) - 1u;
      if (need) {
        while ((__hip_atomic_load(&smask[q], __ATOMIC_ACQUIRE,
                                  __HIP_MEMORY_SCOPE_WORKGROUP) & need) != need) {}
      }
    }

    // ---- Parallel exclusive fold, select-free: read the 7 entries at
    // [wid+k] (k=0..6) — identity pad makes out-of-range waves no-ops.
    // ex = fold oldest-first: ex = a*ex + x over waves 0..wid-1.
    float ex = 0.0f;                     // lane n<4: exclusive x-prefix, state n
    {
      const int n = lane & (NQ - 1);
      #pragma unroll
      for (int k = 0; k < NW - 1; ++k) {
        float2 s = sAXp[q][wid + k][n];
        ex = s.x * ex + s.y;
      }
    }

    // ---- Apply: y_i += cp_i * h0   (pure FMA; exn broadcast via readlane)
    #pragma unroll
    for (int n = 0; n < NQ; ++n) {
      float al = dppf<0x138,0xF>(1.0f, cA[n]);   // lane-exclusive prefix
      float xl = dppf<0x138,0xF>(0.0f, cX[n]);
      float exn = readlane_f(ex, n);             // scalar: wave-exclusive x
      float h0 = al * exn + xl;                  // state entering this chunk
      #pragma unroll
      for (int i = 0; i < T; ++i) y[i] += cp[n][i] * h0;
    }
    // no end-of-pass sync: each pass has its own sAXp buffer + mask word
  }

  // ---- Epilogue: + u*D, * silu(z), store  (u re-loaded here)
  const float Dd = Dv[d];
  const float4* z4 = reinterpret_cast<const float4*>(zm + roff);
  float4 z0 = z4[tid];
  float4 ua = u4[tid];
  float zv[T] = {z0.x, z0.y, z0.z, z0.w};
  float uv[T] = {ua.x, ua.y, ua.z, ua.w};
  float ov[T];
  #pragma unroll
  for (int i = 0; i < T; ++i) {
    float yy  = y[i] + uv[i] * Dd;
    float sig = 1.0f / (1.0f + fast_exp(-zv[i]));
    ov[i] = yy * zv[i] * sig;
  }
  reinterpret_cast<float4*>(out + roff)[tid] = make_float4(ov[0], ov[1], ov[2], ov[3]);
}

extern "C" void kernel_launch(void* const* d_in, const int* in_sizes, int n_in,
                              void* d_out, int out_size, void* d_ws, size_t ws_size,
                              hipStream_t stream)
{
  const float* u  = (const float*)d_in[0];
  const float* dl = (const float*)d_in[1];
  const float* A  = (const float*)d_in[2];
  const float* Bm = (const float*)d_in[3];
  const float* Cm = (const float*)d_in[4];
  const float* Dv = (const float*)d_in[5];
  const float* zm = (const float*)d_in[6];
  float* out = (float*)d_out;
  const int rows = in_sizes[0] / kL;   // b*d = 2048
  selscan_kernel<<<rows, BLOCK, 0, stream>>>(u, dl, A, Bm, Cm, Dv, zm, out);
}